// Round 2
// baseline (400.738 us; speedup 1.0000x reference)
//
#include <hip/hip_runtime.h>
#include <stdint.h>

#define T_TOK 1024
#define H_DIM 1024
#define I_DIM 2816
#define E_NUM 8
#define LSTR 72   // LDS row stride in shorts (64 + 8 pad -> 2-way banks max)

typedef __attribute__((ext_vector_type(8))) short bf16x8;
typedef __attribute__((ext_vector_type(4))) float f32x4;

struct Meta { int counts[E_NUM]; int tiles[E_NUM]; int offs[E_NUM]; };

__device__ __forceinline__ unsigned short f2b(float f) {
    unsigned u = __float_as_uint(f);
    u += 0x7fffu + ((u >> 16) & 1u);   // round-to-nearest-even
    return (unsigned short)(u >> 16);
}
__device__ __forceinline__ ushort4 f2b4(float4 v) {
    ushort4 o; o.x = f2b(v.x); o.y = f2b(v.y); o.z = f2b(v.z); o.w = f2b(v.w); return o;
}

// ---------------- routing: softmax -> top2 -> renorm -> grouped token lists (64-padded) ----
__global__ void route_kernel(const float* __restrict__ logits,
                             int* __restrict__ tok, float* __restrict__ gate,
                             Meta* __restrict__ meta) {
    __shared__ int cnt[E_NUM];
    const int tid = threadIdx.x;   // == token id, blockDim=1024
    if (tid < E_NUM) cnt[tid] = 0;
    for (int j = tid; j < E_NUM * T_TOK; j += 1024) { tok[j] = 0; gate[j] = 0.f; }
    __syncthreads();

    float p[E_NUM];
    const float* lrow = logits + tid * E_NUM;
    float m = -1e30f;
    #pragma unroll
    for (int e = 0; e < E_NUM; ++e) { p[e] = lrow[e]; m = fmaxf(m, p[e]); }
    #pragma unroll
    for (int e = 0; e < E_NUM; ++e) p[e] = __expf(p[e] - m);
    int e0 = 0; float v0 = p[0];
    #pragma unroll
    for (int e = 1; e < E_NUM; ++e) if (p[e] > v0) { v0 = p[e]; e0 = e; }
    int e1 = -1; float v1 = -1.f;
    #pragma unroll
    for (int e = 0; e < E_NUM; ++e) if (e != e0 && p[e] > v1) { v1 = p[e]; e1 = e; }
    const float inv = 1.f / (v0 + v1);       // softmax denom cancels in ratio
    const float g0 = v0 * inv, g1 = v1 * inv;

    const int p0 = atomicAdd(&cnt[e0], 1);
    const int p1 = atomicAdd(&cnt[e1], 1);
    tok[e0 * T_TOK + p0] = tid; gate[e0 * T_TOK + p0] = g0;
    tok[e1 * T_TOK + p1] = tid; gate[e1 * T_TOK + p1] = g1;
    __syncthreads();
    if (tid == 0) {
        int off = 0;
        for (int e = 0; e < E_NUM; ++e) {
            const int c = cnt[e];
            const int t = (c + 63) >> 6;        // 64-row tiles
            meta->counts[e] = c; meta->tiles[e] = t; meta->offs[e] = off;
            off += t * 64;
        }
    }
}

// ---------------- x fp32 -> bf16 ----------------
__global__ void cvt_x_kernel(const float* __restrict__ x, unsigned short* __restrict__ xb) {
    const int i = blockIdx.x * blockDim.x + threadIdx.x;
    const float4 v = ((const float4*)x)[i];
    ((ushort4*)xb)[i] = f2b4(v);
}

// ---------------- GEMM1: act = silu(x@w1^T) * (x@w3^T) ----------------
// grid (44, 8, 16), block 256. Tile 64 tokens x 64 I-cols (dual w1/w3), BK=64.
__launch_bounds__(256, 4)
__global__ void gemm1_kernel(const unsigned short* __restrict__ xb,
                             const float* __restrict__ w1,
                             const float* __restrict__ w3,
                             const int* __restrict__ tok,
                             const Meta* __restrict__ meta,
                             unsigned short* __restrict__ act) {
    const int e = blockIdx.y;
    const int mt = blockIdx.z;
    if (mt >= meta->tiles[e]) return;
    const int it = blockIdx.x;
    const int tid = threadIdx.x;

    __shared__ __align__(16) unsigned short As[64 * LSTR];
    __shared__ __align__(16) unsigned short B1s[64 * LSTR];
    __shared__ __align__(16) unsigned short B3s[64 * LSTR];

    // A staging: 64 rows x 64 k bf16 -> 2 uint4/thread
    const int arow = tid >> 2, asub = tid & 3;
    const int t0 = tok[e * T_TOK + mt * 64 + arow];
    const unsigned short* ap = xb + (size_t)t0 * H_DIM + asub * 8;
    unsigned short* al0 = &As[arow * LSTR + asub * 8];
    unsigned short* al1 = al0 + 32;

    // B staging: 64 rows x 64 k fp32 per matrix -> 4 float4/thread/matrix
    const size_t wb = (size_t)e * I_DIM * H_DIM + (size_t)(it * 64 + arow) * H_DIM;
    const float* b1p = w1 + wb + asub * 4;
    const float* b3p = w3 + wb + asub * 4;
    unsigned short* bl1 = &B1s[arow * LSTR + asub * 4];
    unsigned short* bl3 = &B3s[arow * LSTR + asub * 4];

    const int wave = tid >> 6, lane = tid & 63;
    const int quad = lane >> 4, l15 = lane & 15;
    const int mbase = (wave >> 1) * 32;
    const int nbase = (wave & 1) * 32;

    f32x4 acc1[2][2], acc3[2][2];
    #pragma unroll
    for (int mi = 0; mi < 2; ++mi)
        #pragma unroll
        for (int ni = 0; ni < 2; ++ni) {
            acc1[mi][ni] = (f32x4){0.f, 0.f, 0.f, 0.f};
            acc3[mi][ni] = (f32x4){0.f, 0.f, 0.f, 0.f};
        }

    uint4 ra0 = *(const uint4*)(ap);
    uint4 ra1 = *(const uint4*)(ap + 32);
    float4 r1[4], r3[4];
    #pragma unroll
    for (int j = 0; j < 4; ++j) {
        r1[j] = *(const float4*)(b1p + 16 * j);
        r3[j] = *(const float4*)(b3p + 16 * j);
    }

    const int NK = H_DIM / 64;   // 16
    for (int ks = 0; ks < NK; ++ks) {
        __syncthreads();
        *(uint4*)al0 = ra0;
        *(uint4*)al1 = ra1;
        #pragma unroll
        for (int j = 0; j < 4; ++j) {
            *(ushort4*)(bl1 + 16 * j) = f2b4(r1[j]);
            *(ushort4*)(bl3 + 16 * j) = f2b4(r3[j]);
        }
        __syncthreads();
        if (ks + 1 < NK) {
            const int k0 = (ks + 1) * 64;
            ra0 = *(const uint4*)(ap + k0);
            ra1 = *(const uint4*)(ap + k0 + 32);
            #pragma unroll
            for (int j = 0; j < 4; ++j) {
                r1[j] = *(const float4*)(b1p + k0 + 16 * j);
                r3[j] = *(const float4*)(b3p + k0 + 16 * j);
            }
        }
        #pragma unroll
        for (int kk = 0; kk < 2; ++kk) {
            bf16x8 a[2], b1f[2], b3f[2];
            #pragma unroll
            for (int mi = 0; mi < 2; ++mi)
                a[mi] = *(const bf16x8*)&As[(mbase + mi * 16 + l15) * LSTR + kk * 32 + quad * 8];
            #pragma unroll
            for (int ni = 0; ni < 2; ++ni) {
                b1f[ni] = *(const bf16x8*)&B1s[(nbase + ni * 16 + l15) * LSTR + kk * 32 + quad * 8];
                b3f[ni] = *(const bf16x8*)&B3s[(nbase + ni * 16 + l15) * LSTR + kk * 32 + quad * 8];
            }
            #pragma unroll
            for (int mi = 0; mi < 2; ++mi)
                #pragma unroll
                for (int ni = 0; ni < 2; ++ni) {
                    acc1[mi][ni] = __builtin_amdgcn_mfma_f32_16x16x32_bf16(a[mi], b1f[ni], acc1[mi][ni], 0, 0, 0);
                    acc3[mi][ni] = __builtin_amdgcn_mfma_f32_16x16x32_bf16(a[mi], b3f[ni], acc3[mi][ni], 0, 0, 0);
                }
        }
    }

    const int opad = meta->offs[e];
    #pragma unroll
    for (int mi = 0; mi < 2; ++mi)
        #pragma unroll
        for (int ni = 0; ni < 2; ++ni)
            #pragma unroll
            for (int rr = 0; rr < 4; ++rr) {
                const float v1 = acc1[mi][ni][rr];
                const float v3 = acc3[mi][ni][rr];
                const float s = v1 / (1.f + __expf(-v1)) * v3;
                const int row = opad + mt * 64 + mbase + mi * 16 + quad * 4 + rr;
                const int col = it * 64 + nbase + ni * 16 + l15;
                act[(size_t)row * I_DIM + col] = f2b(s);
            }
}

// ---------------- GEMM2: out[t] += gate * (act @ w2^T), split-K=2 ----------------
// grid (16, 8, 32): z = mt*2 + split. Tile 64 rows x 64 H-cols, BK=64, K/split=1408.
__launch_bounds__(256, 4)
__global__ void gemm2_kernel(const unsigned short* __restrict__ act,
                             const float* __restrict__ w2,
                             const int* __restrict__ tok,
                             const float* __restrict__ gate,
                             const Meta* __restrict__ meta,
                             float* __restrict__ out) {
    const int e = blockIdx.y;
    const int mt = blockIdx.z >> 1;
    const int sp = blockIdx.z & 1;
    if (mt >= meta->tiles[e]) return;
    const int it = blockIdx.x;
    const int tid = threadIdx.x;
    const int opad = meta->offs[e];
    const int kbase = sp * (I_DIM / 2);   // 1408

    __shared__ __align__(16) unsigned short As[64 * LSTR];
    __shared__ __align__(16) unsigned short Bs[64 * LSTR];

    const int arow = tid >> 2, asub = tid & 3;
    const unsigned short* ap = act + (size_t)(opad + mt * 64 + arow) * I_DIM + kbase + asub * 8;
    unsigned short* al0 = &As[arow * LSTR + asub * 8];
    unsigned short* al1 = al0 + 32;

    const size_t wb = (size_t)e * H_DIM * I_DIM + (size_t)(it * 64 + arow) * I_DIM + kbase;
    const float* bp = w2 + wb + asub * 4;
    unsigned short* bl = &Bs[arow * LSTR + asub * 4];

    const int wave = tid >> 6, lane = tid & 63;
    const int quad = lane >> 4, l15 = lane & 15;
    const int mbase = (wave >> 1) * 32;
    const int nbase = (wave & 1) * 32;

    f32x4 acc[2][2];
    #pragma unroll
    for (int mi = 0; mi < 2; ++mi)
        #pragma unroll
        for (int ni = 0; ni < 2; ++ni) acc[mi][ni] = (f32x4){0.f, 0.f, 0.f, 0.f};

    uint4 ra0 = *(const uint4*)(ap);
    uint4 ra1 = *(const uint4*)(ap + 32);
    float4 rb[4];
    #pragma unroll
    for (int j = 0; j < 4; ++j) rb[j] = *(const float4*)(bp + 16 * j);

    const int NK = (I_DIM / 2) / 64;   // 22
    for (int ks = 0; ks < NK; ++ks) {
        __syncthreads();
        *(uint4*)al0 = ra0;
        *(uint4*)al1 = ra1;
        #pragma unroll
        for (int j = 0; j < 4; ++j) *(ushort4*)(bl + 16 * j) = f2b4(rb[j]);
        __syncthreads();
        if (ks + 1 < NK) {
            const int k0 = (ks + 1) * 64;
            ra0 = *(const uint4*)(ap + k0);
            ra1 = *(const uint4*)(ap + k0 + 32);
            #pragma unroll
            for (int j = 0; j < 4; ++j) rb[j] = *(const float4*)(bp + k0 + 16 * j);
        }
        #pragma unroll
        for (int kk = 0; kk < 2; ++kk) {
            bf16x8 a[2], bf[2];
            #pragma unroll
            for (int mi = 0; mi < 2; ++mi)
                a[mi] = *(const bf16x8*)&As[(mbase + mi * 16 + l15) * LSTR + kk * 32 + quad * 8];
            #pragma unroll
            for (int ni = 0; ni < 2; ++ni)
                bf[ni] = *(const bf16x8*)&Bs[(nbase + ni * 16 + l15) * LSTR + kk * 32 + quad * 8];
            #pragma unroll
            for (int mi = 0; mi < 2; ++mi)
                #pragma unroll
                for (int ni = 0; ni < 2; ++ni)
                    acc[mi][ni] = __builtin_amdgcn_mfma_f32_16x16x32_bf16(a[mi], bf[ni], acc[mi][ni], 0, 0, 0);
        }
    }

    // epilogue: out[token][col] += gate * y  (padded rows: gate=0, token=0 -> adds 0)
    #pragma unroll
    for (int mi = 0; mi < 2; ++mi)
        #pragma unroll
        for (int rr = 0; rr < 4; ++rr) {
            const int r = mt * 64 + mbase + mi * 16 + quad * 4 + rr;
            const int t = tok[e * T_TOK + r];
            const float g = gate[e * T_TOK + r];
            #pragma unroll
            for (int ni = 0; ni < 2; ++ni) {
                const int col = it * 64 + nbase + ni * 16 + l15;
                atomicAdd(&out[(size_t)t * H_DIM + col], g * acc[mi][ni][rr]);
            }
        }
}

extern "C" void kernel_launch(void* const* d_in, const int* in_sizes, int n_in,
                              void* d_out, int out_size, void* d_ws, size_t ws_size,
                              hipStream_t stream) {
    const float* x      = (const float*)d_in[0];
    const float* logits = (const float*)d_in[1];
    const float* w1     = (const float*)d_in[2];
    const float* w3     = (const float*)d_in[3];
    const float* w2     = (const float*)d_in[4];
    float* out = (float*)d_out;

    char* ws = (char*)d_ws;
    int*   tok  = (int*)ws;                                   // 32 KB
    float* gate = (float*)(ws + 32768);                       // 32 KB
    Meta*  meta = (Meta*)(ws + 65536);
    unsigned short* xb  = (unsigned short*)(ws + 131072);     // 2 MB
    unsigned short* act = (unsigned short*)(ws + 131072 + 2097152); // <=2560 x 2816 bf16

    hipMemsetAsync(d_out, 0, (size_t)T_TOK * H_DIM * sizeof(float), stream);
    route_kernel<<<1, 1024, 0, stream>>>(logits, tok, gate, meta);
    cvt_x_kernel<<<T_TOK * H_DIM / 4 / 256, 256, 0, stream>>>(x, xb);
    gemm1_kernel<<<dim3(I_DIM / 64, E_NUM, 16), 256, 0, stream>>>(xb, w1, w3, tok, meta, act);
    gemm2_kernel<<<dim3(H_DIM / 64, E_NUM, 32), 256, 0, stream>>>(act, w2, tok, gate, meta, out);
}